// Round 9
// baseline (439.751 us; speedup 1.0000x reference)
//
#include <hip/hip_runtime.h>
#include <hip/hip_bf16.h>

// Contrastive loss: N=4096, V=2, D=256.  M=8192 view-major rows.
// loss = mean_i [ log sum_{j!=i} exp(l_ij/T) - l_{i,pos}/T ],  l = norm(A)@norm(B)^T.
// Round 9: m97-faithful 128x128 tile, 256 thr (4 waves 2x2, wave 64x64),
// BK=64, LDS 64KB A+B double-buffer -> 2 blocks/CU (m114 cross-block overlap
// covers barrier drains).  One barrier per K-tile: {vmcnt(0); barrier;
// stage(t+1); ds_read+MFMA}.  Full-K acc -> epilogue once after the loop.
// Rounds 4-8 lesson: never exceed ~100 arch VGPRs; acc[4][4]=64 on acc side.

#define N_SAMP 4096
#define DIM    256
#define M_ROWS 8192
#define TEMP   0.07f

using short8 = __attribute__((ext_vector_type(8))) short;
using f32x4  = __attribute__((ext_vector_type(4))) float;

#define GLDS(g, l) __builtin_amdgcn_global_load_lds( \
    (const __attribute__((address_space(1))) void*)(g), \
    (__attribute__((address_space(3))) void*)(l), 16, 0, 0)

// ---------------------------------------------------------------------------
// Normalize rows (view-major) -> bf16; zero S / PosSum / cnt.
// ---------------------------------------------------------------------------
__global__ __launch_bounds__(256) void norm_kernel(
    const float* __restrict__ A, const float* __restrict__ B,
    unsigned short* __restrict__ Ah, unsigned short* __restrict__ Bh,
    float* __restrict__ S, float* __restrict__ PosSum, int* __restrict__ cnt)
{
  int tid = threadIdx.x;
  if (blockIdx.x < 8)
    ((float4*)S)[blockIdx.x * 256 + tid] = (float4){0.f, 0.f, 0.f, 0.f};
  if (blockIdx.x == 8 && tid == 0) { PosSum[0] = 0.f; cnt[0] = 0; }

  int wave = tid >> 6, lane = tid & 63;
  int gw   = blockIdx.x * 4 + wave;          // 0 .. 2*M-1
  const float* src; unsigned short* dst; int m;
  if (gw < M_ROWS) { src = A; dst = Ah; m = gw; }
  else             { src = B; dst = Bh; m = gw - M_ROWS; }
  int n = m & (N_SAMP - 1);
  int v = m >> 12;
  const float4* in = (const float4*)(src + (size_t)(n * 2 + v) * DIM);
  float4 x = in[lane];
  float ss = x.x*x.x + x.y*x.y + x.z*x.z + x.w*x.w;
  #pragma unroll
  for (int d = 1; d < 64; d <<= 1) ss += __shfl_xor(ss, d);
  float scale = 1.0f / fmaxf(sqrtf(ss), 1e-12f);
  float vals[4] = {x.x*scale, x.y*scale, x.z*scale, x.w*scale};
  ushort4 o;
  unsigned short* op = (unsigned short*)&o;
  #pragma unroll
  for (int k = 0; k < 4; ++k) {              // f32 -> bf16 RNE
    unsigned int u = __float_as_uint(vals[k]);
    u += 0x7fffu + ((u >> 16) & 1u);
    op[k] = (unsigned short)(u >> 16);
  }
  *(ushort4*)(dst + (size_t)m * DIM + lane * 4) = o;
}

// ---------------------------------------------------------------------------
// 128x128-tile GEMM, full K per block, fused LSE epilogue + final reduction.
// ---------------------------------------------------------------------------
__global__ __launch_bounds__(256, 2) void gemm_lse_kernel(
    const unsigned short* __restrict__ Ah, const unsigned short* __restrict__ Bh,
    float* __restrict__ S, float* __restrict__ PosSum, int* __restrict__ cnt,
    float* __restrict__ out)
{
  __shared__ alignas(16) char lds[2][32768];  // [buf]{A 16KB | B 16KB}
  __shared__ float redbuf[4];
  __shared__ int lastFlag;

  int tid  = threadIdx.x;
  int lane = tid & 63;
  int w    = tid >> 6;
  int wrow = w >> 1, wcol = w & 1;           // 2x2 wave grid; wave = 64x64
  int row0 = blockIdx.y * 128;
  int col0 = blockIdx.x * 128;

  // stage K-tile kt (A 128x64 + B 128x64 = 32KB): 8 GLDS x 16B per thread.
  // Source chunk XOR-swizzled (involution matches the ds_read swizzle).
  auto stage = [&](int kt, int buf) {
    char* dstA = lds[buf];
    char* dstB = lds[buf] + 16384;
    const char* srcA = (const char*)Ah + kt * 128;
    const char* srcB = (const char*)Bh + kt * 128;
    #pragma unroll
    for (int s = 0; s < 4; ++s) {
      int f = s * 256 + tid;                 // 0..1023
      int r = f >> 3, cd = f & 7;            // row 0..127, chunk 0..7
      int cs = cd ^ (r & 7);
      GLDS(srcA + (size_t)(row0 + r) * 512 + cs * 16, dstA + f * 16);
    }
    #pragma unroll
    for (int s = 0; s < 4; ++s) {
      int f = s * 256 + tid;
      int r = f >> 3, cd = f & 7;
      int cs = cd ^ (r & 7);
      GLDS(srcB + (size_t)(col0 + r) * 512 + cs * 16, dstB + f * 16);
    }
  };
  stage(0, 0);

  f32x4 acc[4][4];
  #pragma unroll
  for (int i = 0; i < 4; ++i)
    #pragma unroll
    for (int j = 0; j < 4; ++j)
      acc[i][j] = (f32x4){0.f, 0.f, 0.f, 0.f};

  #pragma unroll
  for (int t = 0; t < 4; ++t) {
    asm volatile("s_waitcnt vmcnt(0)" ::: "memory");   // K-tile t landed
    __builtin_amdgcn_s_barrier();
    __builtin_amdgcn_sched_barrier(0);
    if (t < 3) stage(t + 1, (t + 1) & 1);    // hides under this tile's MFMA

    const char* Acur = lds[t & 1];
    const char* Bcur = lds[t & 1] + 16384;
    short8 a[4][2], b[4][2];
    #pragma unroll
    for (int fm = 0; fm < 4; ++fm) {
      int ar = wrow * 64 + fm * 16 + (lane & 15);
      #pragma unroll
      for (int kk = 0; kk < 2; ++kk) {
        int ca = kk * 4 + (lane >> 4);
        a[fm][kk] = *(const short8*)(Acur + ar * 128 + ((ca ^ (ar & 7)) * 16));
      }
    }
    #pragma unroll
    for (int fn = 0; fn < 4; ++fn) {
      int br = wcol * 64 + fn * 16 + (lane & 15);
      #pragma unroll
      for (int kk = 0; kk < 2; ++kk) {
        int cb = kk * 4 + (lane >> 4);
        b[fn][kk] = *(const short8*)(Bcur + br * 128 + ((cb ^ (br & 7)) * 16));
      }
    }
    __builtin_amdgcn_s_setprio(1);
    #pragma unroll
    for (int kk = 0; kk < 2; ++kk)
      #pragma unroll
      for (int i = 0; i < 4; ++i)
        #pragma unroll
        for (int j = 0; j < 4; ++j)
          acc[i][j] = __builtin_amdgcn_mfma_f32_16x16x32_bf16(a[i][kk], b[j][kk], acc[i][j], 0, 0, 0);
    __builtin_amdgcn_s_setprio(0);
  }

  // ---- fused epilogue: exp-sum per row, positives, global accumulate.
  const float KE = (float)(1.4426950408889634 / 0.07);  // log2(e)/T
  float ssum[4][4];
  #pragma unroll
  for (int i = 0; i < 4; ++i)
    #pragma unroll
    for (int r = 0; r < 4; ++r) ssum[i][r] = 0.f;
  float psum = 0.f;

  #pragma unroll
  for (int fm = 0; fm < 4; ++fm) {
    #pragma unroll
    for (int fn = 0; fn < 4; ++fn) {
      int gj = col0 + wcol * 64 + fn * 16 + (lane & 15);
      #pragma unroll
      for (int r = 0; r < 4; ++r) {
        int gi = row0 + wrow * 64 + fm * 16 + (lane >> 4) * 4 + r;
        float l = acc[fm][fn][r];
        float e = exp2f(l * KE);
        if (((gi ^ gj) & (N_SAMP - 1)) == 0) {
          if (gi == gj) e = 0.f;             // diagonal excluded
          else psum += l;                    // the one positive for row gi
        }
        ssum[fm][r] += e;
      }
    }
  }
  #pragma unroll
  for (int fm = 0; fm < 4; ++fm) {
    #pragma unroll
    for (int r = 0; r < 4; ++r) {
      float v = ssum[fm][r];
      v += __shfl_xor(v, 1);
      v += __shfl_xor(v, 2);
      v += __shfl_xor(v, 4);
      v += __shfl_xor(v, 8);
      if ((lane & 15) == 0) {
        int gi = row0 + wrow * 64 + fm * 16 + (lane >> 4) * 4 + r;
        atomicAdd(&S[gi], v);
      }
    }
  }
  float pv = psum;
  #pragma unroll
  for (int d = 1; d < 64; d <<= 1) pv += __shfl_xor(pv, d);
  if (lane == 0) redbuf[w] = pv;
  __syncthreads();
  if (tid == 0) {
    float tsum = redbuf[0] + redbuf[1] + redbuf[2] + redbuf[3];
    atomicAdd(PosSum, tsum);
  }

  // ---- completion counter; last of 4096 blocks computes the loss.
  __threadfence();
  if (tid == 0) lastFlag = (atomicAdd(cnt, 1) == 4095);
  __syncthreads();
  if (lastFlag) {
    __threadfence();
    float part = 0.f;
    for (int i = tid; i < M_ROWS; i += 256)
      part += logf(atomicAdd(&S[i], 0.0f));  // coherent read
    #pragma unroll
    for (int d = 1; d < 64; d <<= 1) part += __shfl_xor(part, d);
    __syncthreads();                         // redbuf reuse
    if (lane == 0) redbuf[w] = part;
    __syncthreads();
    if (tid == 0) {
      float sl = redbuf[0] + redbuf[1] + redbuf[2] + redbuf[3];
      float ps = atomicAdd(PosSum, 0.0f);    // coherent read
      out[0] = sl / (float)M_ROWS - ps / ((float)M_ROWS * TEMP);
    }
  }
}

extern "C" void kernel_launch(void* const* d_in, const int* in_sizes, int n_in,
                              void* d_out, int out_size, void* d_ws, size_t ws_size,
                              hipStream_t stream)
{
  const float* A = (const float*)d_in[0];
  const float* B = (const float*)d_in[1];
  char* ws = (char*)d_ws;
  unsigned short* Ah = (unsigned short*)ws;                                  // 4 MB
  unsigned short* Bh = (unsigned short*)(ws + (size_t)M_ROWS * DIM * 2);     // 4 MB
  float* S      = (float*)(ws + 2 * (size_t)M_ROWS * DIM * 2);               // 32 KB
  float* PosSum = S + M_ROWS;
  int*   cnt    = (int*)(PosSum + 1);

  norm_kernel<<<dim3(2 * M_ROWS / 4), 256, 0, stream>>>(A, B, Ah, Bh, S, PosSum, cnt);
  gemm_lse_kernel<<<dim3(64, 64), 256, 0, stream>>>(Ah, Bh, S, PosSum, cnt, (float*)d_out);
}